// Round 1
// baseline (401.518 us; speedup 1.0000x reference)
//
#include <hip/hip_runtime.h>
#include <math.h>

#define N_ROWS (32 * 64 * 64)   // 131072 rows
#define KCODES 1024
#define DIM 64

// d_ws layout:
//   [0, 8)              double loss_sum
//   [16, 16+4096)       int counts[1024]
//   [16+4096, +4096)    float bnorm[1024]
#define WS_COUNTS_OFF 16
#define WS_BNORM_OFF  (16 + 4096)
#define WS_ZERO_BYTES (16 + 4096)

__global__ void vq_bnorm_kernel(const float* __restrict__ emb,
                                float* __restrict__ bnorm) {
    int k = blockIdx.x * blockDim.x + threadIdx.x;
    if (k < KCODES) {
        const float* e = emb + k * DIM;
        float s = 0.f;
#pragma unroll
        for (int d = 0; d < DIM; ++d) s = fmaf(e[d], e[d], s);
        bnorm[k] = s;
    }
}

__launch_bounds__(256)
__global__ void vq_main_kernel(const float* __restrict__ x,
                               const float* __restrict__ emb,
                               const float* __restrict__ bnorm,
                               float* __restrict__ out,
                               int* __restrict__ counts,
                               double* __restrict__ loss_sum) {
    const int row = blockIdx.x * blockDim.x + threadIdx.x;

    // Load my row (64 fp32) into registers.
    float xr[DIM];
    const float* xp = x + (size_t)row * DIM;
#pragma unroll
    for (int d = 0; d < DIM; d += 4) {
        float4 v = *reinterpret_cast<const float4*>(xp + d);
        xr[d] = v.x; xr[d + 1] = v.y; xr[d + 2] = v.z; xr[d + 3] = v.w;
    }

    // a_norm = ||x||^2 (fp32, like the reference)
    float an = 0.f;
#pragma unroll
    for (int d = 0; d < DIM; ++d) an = fmaf(xr[d], xr[d], an);

    // Argmin over codes. k is wave-uniform -> embedding reads are scalar
    // (broadcast) loads; only the FMAs occupy the VALU.
    float best = INFINITY;
    int bk = 0;
    for (int k = 0; k < KCODES; ++k) {
        const float* ek = emb + k * DIM;
        float s0 = 0.f, s1 = 0.f, s2 = 0.f, s3 = 0.f;
#pragma unroll
        for (int d = 0; d < DIM; d += 4) {
            s0 = fmaf(xr[d],     ek[d],     s0);
            s1 = fmaf(xr[d + 1], ek[d + 1], s1);
            s2 = fmaf(xr[d + 2], ek[d + 2], s2);
            s3 = fmaf(xr[d + 3], ek[d + 3], s3);
        }
        float dot = (s0 + s1) + (s2 + s3);
        // Same formula/order as the reference: (a_norm + b_norm) - 2*matmul
        float dist = fmaxf((an + bnorm[k]) - 2.0f * dot, 0.f);
        if (dist < best) { best = dist; bk = k; }   // strict '<' = first index
    }

    // Gather the chosen code, write quantized output, accumulate loss partial.
    const float* eb = emb + (size_t)bk * DIM;
    float* op = out + (size_t)row * DIM;
    float lsum = 0.f;
#pragma unroll
    for (int d = 0; d < DIM; d += 4) {
        float4 q;
        q.x = eb[d]; q.y = eb[d + 1]; q.z = eb[d + 2]; q.w = eb[d + 3];
        *reinterpret_cast<float4*>(op + d) = q;
        float dx = q.x - xr[d];     lsum = fmaf(dx, dx, lsum);
        dx = q.y - xr[d + 1];       lsum = fmaf(dx, dx, lsum);
        dx = q.z - xr[d + 2];       lsum = fmaf(dx, dx, lsum);
        dx = q.w - xr[d + 3];       lsum = fmaf(dx, dx, lsum);
    }

    atomicAdd(&counts[bk], 1);

    // Block-level loss reduction in double, one global atomic per block.
    double dsum = (double)lsum;
#pragma unroll
    for (int off = 32; off > 0; off >>= 1) dsum += __shfl_down(dsum, off);

    __shared__ double red[4];   // 256 threads = 4 waves
    const int lane = threadIdx.x & 63;
    const int wid  = threadIdx.x >> 6;
    if (lane == 0) red[wid] = dsum;
    __syncthreads();
    if (threadIdx.x == 0) {
        double s = red[0] + red[1] + red[2] + red[3];
        atomicAdd(loss_sum, s);
    }
}

__global__ void vq_final_kernel(const int* __restrict__ counts,
                                const double* __restrict__ loss_sum,
                                float* __restrict__ out) {
    __shared__ double red[16];
    const int t = threadIdx.x;           // 1024 threads
    float p = (float)counts[t] / (float)N_ROWS;
    double term = (double)p * log((double)p + 1e-10);
#pragma unroll
    for (int off = 32; off > 0; off >>= 1) term += __shfl_down(term, off);
    if ((t & 63) == 0) red[t >> 6] = term;
    __syncthreads();
    if (t == 0) {
        double s = 0.0;
#pragma unroll
        for (int w = 0; w < 16; ++w) s += red[w];
        const size_t base = (size_t)N_ROWS * DIM;
        out[base]     = (float)(1.5 * (*loss_sum) / (double)((size_t)N_ROWS * DIM));
        out[base + 1] = (float)exp(-s);
    }
}

extern "C" void kernel_launch(void* const* d_in, const int* in_sizes, int n_in,
                              void* d_out, int out_size, void* d_ws, size_t ws_size,
                              hipStream_t stream) {
    const float* x   = (const float*)d_in[0];
    const float* emb = (const float*)d_in[1];
    float* out = (float*)d_out;

    double* loss_sum = (double*)d_ws;
    int*    counts   = (int*)((char*)d_ws + WS_COUNTS_OFF);
    float*  bnorm    = (float*)((char*)d_ws + WS_BNORM_OFF);

    hipMemsetAsync(d_ws, 0, WS_ZERO_BYTES, stream);

    vq_bnorm_kernel<<<KCODES / 256, 256, 0, stream>>>(emb, bnorm);
    vq_main_kernel<<<N_ROWS / 256, 256, 0, stream>>>(x, emb, bnorm, out,
                                                     counts, loss_sum);
    vq_final_kernel<<<1, 1024, 0, stream>>>(counts, loss_sum, out);
}

// Round 2
// 291.826 us; speedup vs baseline: 1.3759x; 1.3759x over previous
//
#include <hip/hip_runtime.h>
#include <math.h>

#define N_ROWS (32 * 64 * 64)   // 131072 rows
#define KCODES 1024
#define DIM 64
#define KSPLIT 4
#define KCHUNK (KCODES / KSPLIT)   // 256 codes per partial block

// d_ws layout:
//   [0, 8)              double loss_sum
//   [16, 16+4096)       int counts[1024]
//   [16+4096, +4096)    float bnorm[1024]
//   [32768, +4MB)       u64 packed[KSPLIT][N_ROWS]  (dist_bits<<32 | k)
#define WS_COUNTS_OFF 16
#define WS_BNORM_OFF  (16 + 4096)
#define WS_PACKED_OFF 32768
#define WS_ZERO_BYTES (16 + 4096)

__global__ void vq_bnorm_kernel(const float* __restrict__ emb,
                                float* __restrict__ bnorm) {
    int k = blockIdx.x * blockDim.x + threadIdx.x;
    if (k < KCODES) {
        const float* e = emb + k * DIM;
        float s = 0.f;
#pragma unroll
        for (int d = 0; d < DIM; ++d) s = fmaf(e[d], e[d], s);
        bnorm[k] = s;
    }
}

// Pass 1: each block scans KCHUNK codes for 256 rows, emits packed partial
// argmin. dist >= 0 (fmax clamp) so float bits compare like the float; packed
// u64 lexicographic min == (min dist, then min k) == first-index argmin,
// bit-identical to the reference's semantics.
__launch_bounds__(256)
__global__ void vq_argmin_kernel(const float* __restrict__ x,
                                 const float* __restrict__ emb,
                                 const float* __restrict__ bnorm,
                                 unsigned long long* __restrict__ packed) {
    const int kc     = blockIdx.x & (KSPLIT - 1);   // XCD round-robin -> each
    const int rowblk = blockIdx.x >> 2;             // XCD sees few k-slices
    const int row = rowblk * 256 + threadIdx.x;
    const int k0 = kc * KCHUNK;

    float xr[DIM];
    const float* xp = x + (size_t)row * DIM;
#pragma unroll
    for (int d = 0; d < DIM; d += 4) {
        float4 v = *reinterpret_cast<const float4*>(xp + d);
        xr[d] = v.x; xr[d + 1] = v.y; xr[d + 2] = v.z; xr[d + 3] = v.w;
    }

    float an = 0.f;
#pragma unroll
    for (int d = 0; d < DIM; ++d) an = fmaf(xr[d], xr[d], an);

    float best = INFINITY;
    int bk = k0;
#pragma unroll 2
    for (int k = k0; k < k0 + KCHUNK; ++k) {
        const float* ek = emb + k * DIM;   // k wave-uniform -> scalar loads
        float s0 = 0.f, s1 = 0.f, s2 = 0.f, s3 = 0.f;
#pragma unroll
        for (int d = 0; d < DIM; d += 4) {
            s0 = fmaf(xr[d],     ek[d],     s0);
            s1 = fmaf(xr[d + 1], ek[d + 1], s1);
            s2 = fmaf(xr[d + 2], ek[d + 2], s2);
            s3 = fmaf(xr[d + 3], ek[d + 3], s3);
        }
        float dot = (s0 + s1) + (s2 + s3);
        // exact reference order: (a_norm + b_norm) - 2*dot, clamped at 0
        float dist = fmaxf((an + bnorm[k]) - 2.0f * dot, 0.f);
        if (dist < best) { best = dist; bk = k; }
    }

    packed[(size_t)kc * N_ROWS + row] =
        ((unsigned long long)__float_as_uint(best) << 32) | (unsigned)bk;
}

// Pass 2: combine partials, gather code, write quantized, loss + histogram.
__launch_bounds__(256)
__global__ void vq_gather_kernel(const float* __restrict__ x,
                                 const float* __restrict__ emb,
                                 const unsigned long long* __restrict__ packed,
                                 float* __restrict__ out,
                                 int* __restrict__ counts,
                                 double* __restrict__ loss_sum) {
    const int row = blockIdx.x * blockDim.x + threadIdx.x;

    unsigned long long best = packed[row];
#pragma unroll
    for (int j = 1; j < KSPLIT; ++j) {
        unsigned long long c = packed[(size_t)j * N_ROWS + row];
        if (c < best) best = c;
    }
    const int bk = (int)(best & 0xFFFFFFFFu);

    const float* eb = emb + (size_t)bk * DIM;
    const float* xp = x + (size_t)row * DIM;
    float* op = out + (size_t)row * DIM;
    float lsum = 0.f;
#pragma unroll
    for (int d = 0; d < DIM; d += 4) {
        float4 q;
        q.x = eb[d]; q.y = eb[d + 1]; q.z = eb[d + 2]; q.w = eb[d + 3];
        float4 v = *reinterpret_cast<const float4*>(xp + d);
        *reinterpret_cast<float4*>(op + d) = q;
        float dx = q.x - v.x; lsum = fmaf(dx, dx, lsum);
        dx = q.y - v.y;       lsum = fmaf(dx, dx, lsum);
        dx = q.z - v.z;       lsum = fmaf(dx, dx, lsum);
        dx = q.w - v.w;       lsum = fmaf(dx, dx, lsum);
    }

    atomicAdd(&counts[bk], 1);

    double dsum = (double)lsum;
#pragma unroll
    for (int off = 32; off > 0; off >>= 1) dsum += __shfl_down(dsum, off);

    __shared__ double red[4];
    const int lane = threadIdx.x & 63;
    const int wid  = threadIdx.x >> 6;
    if (lane == 0) red[wid] = dsum;
    __syncthreads();
    if (threadIdx.x == 0) {
        double s = red[0] + red[1] + red[2] + red[3];
        atomicAdd(loss_sum, s);
    }
}

__global__ void vq_final_kernel(const int* __restrict__ counts,
                                const double* __restrict__ loss_sum,
                                float* __restrict__ out) {
    __shared__ double red[16];
    const int t = threadIdx.x;           // 1024 threads
    float p = (float)counts[t] / (float)N_ROWS;
    double term = (double)p * log((double)p + 1e-10);
#pragma unroll
    for (int off = 32; off > 0; off >>= 1) term += __shfl_down(term, off);
    if ((t & 63) == 0) red[t >> 6] = term;
    __syncthreads();
    if (t == 0) {
        double s = 0.0;
#pragma unroll
        for (int w = 0; w < 16; ++w) s += red[w];
        const size_t base = (size_t)N_ROWS * DIM;
        out[base]     = (float)(1.5 * (*loss_sum) / (double)((size_t)N_ROWS * DIM));
        out[base + 1] = (float)exp(-s);
    }
}

extern "C" void kernel_launch(void* const* d_in, const int* in_sizes, int n_in,
                              void* d_out, int out_size, void* d_ws, size_t ws_size,
                              hipStream_t stream) {
    const float* x   = (const float*)d_in[0];
    const float* emb = (const float*)d_in[1];
    float* out = (float*)d_out;

    double* loss_sum = (double*)d_ws;
    int*    counts   = (int*)((char*)d_ws + WS_COUNTS_OFF);
    float*  bnorm    = (float*)((char*)d_ws + WS_BNORM_OFF);
    unsigned long long* packed =
        (unsigned long long*)((char*)d_ws + WS_PACKED_OFF);

    hipMemsetAsync(d_ws, 0, WS_ZERO_BYTES, stream);

    vq_bnorm_kernel<<<KCODES / 256, 256, 0, stream>>>(emb, bnorm);
    vq_argmin_kernel<<<(N_ROWS / 256) * KSPLIT, 256, 0, stream>>>(x, emb, bnorm,
                                                                  packed);
    vq_gather_kernel<<<N_ROWS / 256, 256, 0, stream>>>(x, emb, packed, out,
                                                       counts, loss_sum);
    vq_final_kernel<<<1, 1024, 0, stream>>>(counts, loss_sum, out);
}

// Round 3
// 266.975 us; speedup vs baseline: 1.5040x; 1.0931x over previous
//
#include <hip/hip_runtime.h>
#include <math.h>

#define N_ROWS (32 * 64 * 64)   // 131072 rows
#define KCODES 1024
#define DIM 64
#define ROWS_PER_BLOCK 512      // 256 threads x 2 rows each
#define NUM_RB (N_ROWS / ROWS_PER_BLOCK)   // 256 row-blocks

// d_ws layout:
//   [0, 8)              double loss_sum
//   [16, 16+4096)       int counts[1024]
//   [16+4096, +4096)    float bnorm[1024]
//   [32768, +KS*1MB)    u64 packed[KS][N_ROWS]  (dist_bits<<32 | k)
#define WS_COUNTS_OFF 16
#define WS_BNORM_OFF  (16 + 4096)
#define WS_PACKED_OFF 32768
#define WS_ZERO_BYTES (16 + 4096)

__global__ void vq_bnorm_kernel(const float* __restrict__ emb,
                                float* __restrict__ bnorm) {
    int k = blockIdx.x * blockDim.x + threadIdx.x;
    if (k < KCODES) {
        const float* e = emb + k * DIM;
        float s = 0.f;
#pragma unroll
        for (int d = 0; d < DIM; ++d) s = fmaf(e[d], e[d], s);
        bnorm[k] = s;
    }
}

// Pass 1: 2 rows per thread; each block scans KCODES/KS codes.
// Mapping: rb = b % NUM_RB, kc = b / NUM_RB -> b%8 == rb%8, so all KS splits
// of a row-block land on the same XCD; per-XCD x slice = 4 MB = its L2.
// Numerics per (row,k) are bit-identical to the previously passing kernel:
// same 4-accumulator fmaf dot, same (an + bnorm[k]) - 2*dot, fmax 0, strict <.
template <int KS>
__launch_bounds__(256, 3)
__global__ void vq_argmin_kernel(const float* __restrict__ x,
                                 const float* __restrict__ emb,
                                 const float* __restrict__ bnorm,
                                 unsigned long long* __restrict__ packed) {
    constexpr int KCHUNK = KCODES / KS;
    const int rb = blockIdx.x % NUM_RB;
    const int kc = blockIdx.x / NUM_RB;
    const int row0 = rb * ROWS_PER_BLOCK + threadIdx.x;
    const int row1 = row0 + 256;
    const int k0 = kc * KCHUNK;

    float xr0[DIM], xr1[DIM];
    {
        const float* xp0 = x + (size_t)row0 * DIM;
        const float* xp1 = x + (size_t)row1 * DIM;
#pragma unroll
        for (int d = 0; d < DIM; d += 4) {
            float4 v0 = *reinterpret_cast<const float4*>(xp0 + d);
            xr0[d] = v0.x; xr0[d + 1] = v0.y; xr0[d + 2] = v0.z; xr0[d + 3] = v0.w;
            float4 v1 = *reinterpret_cast<const float4*>(xp1 + d);
            xr1[d] = v1.x; xr1[d + 1] = v1.y; xr1[d + 2] = v1.z; xr1[d + 3] = v1.w;
        }
    }

    float an0 = 0.f, an1 = 0.f;
#pragma unroll
    for (int d = 0; d < DIM; ++d) an0 = fmaf(xr0[d], xr0[d], an0);
#pragma unroll
    for (int d = 0; d < DIM; ++d) an1 = fmaf(xr1[d], xr1[d], an1);

    float best0 = INFINITY, best1 = INFINITY;
    int bk0 = k0, bk1 = k0;
    for (int k = k0; k < k0 + KCHUNK; ++k) {
        const float* ek = emb + k * DIM;   // k wave-uniform -> scalar loads
        const float bn = bnorm[k];
        float s0 = 0.f, s1 = 0.f, s2 = 0.f, s3 = 0.f;
        float t0 = 0.f, t1 = 0.f, t2 = 0.f, t3 = 0.f;
#pragma unroll
        for (int d = 0; d < DIM; d += 4) {
            float e0 = ek[d], e1 = ek[d + 1], e2 = ek[d + 2], e3 = ek[d + 3];
            s0 = fmaf(xr0[d],     e0, s0);
            s1 = fmaf(xr0[d + 1], e1, s1);
            s2 = fmaf(xr0[d + 2], e2, s2);
            s3 = fmaf(xr0[d + 3], e3, s3);
            t0 = fmaf(xr1[d],     e0, t0);
            t1 = fmaf(xr1[d + 1], e1, t1);
            t2 = fmaf(xr1[d + 2], e2, t2);
            t3 = fmaf(xr1[d + 3], e3, t3);
        }
        float dot0 = (s0 + s1) + (s2 + s3);
        float dot1 = (t0 + t1) + (t2 + t3);
        float dist0 = fmaxf((an0 + bn) - 2.0f * dot0, 0.f);
        float dist1 = fmaxf((an1 + bn) - 2.0f * dot1, 0.f);
        if (dist0 < best0) { best0 = dist0; bk0 = k; }
        if (dist1 < best1) { best1 = dist1; bk1 = k; }
    }

    packed[(size_t)kc * N_ROWS + row0] =
        ((unsigned long long)__float_as_uint(best0) << 32) | (unsigned)bk0;
    packed[(size_t)kc * N_ROWS + row1] =
        ((unsigned long long)__float_as_uint(best1) << 32) | (unsigned)bk1;
}

// Pass 2: combine partials, gather code, write quantized, loss + histogram.
template <int KS>
__launch_bounds__(256)
__global__ void vq_gather_kernel(const float* __restrict__ x,
                                 const float* __restrict__ emb,
                                 const unsigned long long* __restrict__ packed,
                                 float* __restrict__ out,
                                 int* __restrict__ counts,
                                 double* __restrict__ loss_sum) {
    const int row = blockIdx.x * blockDim.x + threadIdx.x;

    unsigned long long best = packed[row];
#pragma unroll
    for (int j = 1; j < KS; ++j) {
        unsigned long long c = packed[(size_t)j * N_ROWS + row];
        if (c < best) best = c;   // lexicographic: min dist, then min k
    }
    const int bk = (int)(best & 0xFFFFFFFFu);

    const float* eb = emb + (size_t)bk * DIM;
    const float* xp = x + (size_t)row * DIM;
    float* op = out + (size_t)row * DIM;
    float lsum = 0.f;
#pragma unroll
    for (int d = 0; d < DIM; d += 4) {
        float4 q;
        q.x = eb[d]; q.y = eb[d + 1]; q.z = eb[d + 2]; q.w = eb[d + 3];
        float4 v = *reinterpret_cast<const float4*>(xp + d);
        *reinterpret_cast<float4*>(op + d) = q;
        float dx = q.x - v.x; lsum = fmaf(dx, dx, lsum);
        dx = q.y - v.y;       lsum = fmaf(dx, dx, lsum);
        dx = q.z - v.z;       lsum = fmaf(dx, dx, lsum);
        dx = q.w - v.w;       lsum = fmaf(dx, dx, lsum);
    }

    atomicAdd(&counts[bk], 1);

    double dsum = (double)lsum;
#pragma unroll
    for (int off = 32; off > 0; off >>= 1) dsum += __shfl_down(dsum, off);

    __shared__ double red[4];
    const int lane = threadIdx.x & 63;
    const int wid  = threadIdx.x >> 6;
    if (lane == 0) red[wid] = dsum;
    __syncthreads();
    if (threadIdx.x == 0) {
        double s = red[0] + red[1] + red[2] + red[3];
        atomicAdd(loss_sum, s);
    }
}

__global__ void vq_final_kernel(const int* __restrict__ counts,
                                const double* __restrict__ loss_sum,
                                float* __restrict__ out) {
    __shared__ double red[16];
    const int t = threadIdx.x;           // 1024 threads
    float p = (float)counts[t] / (float)N_ROWS;
    double term = (double)p * log((double)p + 1e-10);
#pragma unroll
    for (int off = 32; off > 0; off >>= 1) term += __shfl_down(term, off);
    if ((t & 63) == 0) red[t >> 6] = term;
    __syncthreads();
    if (t == 0) {
        double s = 0.0;
#pragma unroll
        for (int w = 0; w < 16; ++w) s += red[w];
        const size_t base = (size_t)N_ROWS * DIM;
        out[base]     = (float)(1.5 * (*loss_sum) / (double)((size_t)N_ROWS * DIM));
        out[base + 1] = (float)exp(-s);
    }
}

extern "C" void kernel_launch(void* const* d_in, const int* in_sizes, int n_in,
                              void* d_out, int out_size, void* d_ws, size_t ws_size,
                              hipStream_t stream) {
    const float* x   = (const float*)d_in[0];
    const float* emb = (const float*)d_in[1];
    float* out = (float*)d_out;

    double* loss_sum = (double*)d_ws;
    int*    counts   = (int*)((char*)d_ws + WS_COUNTS_OFF);
    float*  bnorm    = (float*)((char*)d_ws + WS_BNORM_OFF);
    unsigned long long* packed =
        (unsigned long long*)((char*)d_ws + WS_PACKED_OFF);

    hipMemsetAsync(d_ws, 0, WS_ZERO_BYTES, stream);

    vq_bnorm_kernel<<<KCODES / 256, 256, 0, stream>>>(emb, bnorm);

    const size_t need8 = (size_t)WS_PACKED_OFF + 8ull * N_ROWS * 8ull;
    if (ws_size >= need8) {
        vq_argmin_kernel<8><<<NUM_RB * 8, 256, 0, stream>>>(x, emb, bnorm, packed);
        vq_gather_kernel<8><<<N_ROWS / 256, 256, 0, stream>>>(x, emb, packed, out,
                                                              counts, loss_sum);
    } else {
        vq_argmin_kernel<4><<<NUM_RB * 4, 256, 0, stream>>>(x, emb, bnorm, packed);
        vq_gather_kernel<4><<<N_ROWS / 256, 256, 0, stream>>>(x, emb, packed, out,
                                                              counts, loss_sum);
    }

    vq_final_kernel<<<1, 1024, 0, stream>>>(counts, loss_sum, out);
}